// Round 4
// baseline (857.708 us; speedup 1.0000x reference)
//
#include <hip/hip_runtime.h>
#include <hip/hip_bf16.h>
#include <stdint.h>

typedef __bf16 bf16x8 __attribute__((ext_vector_type(8)));
typedef float f32x4 __attribute__((ext_vector_type(4)));
typedef unsigned short u16x8 __attribute__((ext_vector_type(8)));

#define B_ROWS 8192
#define K_DIM  2048
#define O_DIM  256
#define N_BINS 64
#define J_DIM  (O_DIM * N_BINS)   // 16384

__device__ __forceinline__ unsigned short f2bf(float f) {
    union { float f; unsigned u; } v; v.f = f;
    unsigned r = (v.u + 0x7fffu + ((v.u >> 16) & 1u)) >> 16;
    return (unsigned short)r;
}

// ---- conversion kernels ------------------------------------------------
__global__ void cvt_x_kernel(const float* __restrict__ x, unsigned short* __restrict__ xb) {
    int i = (blockIdx.x * 256 + threadIdx.x) * 4;
    float4 v = *(const float4*)(x + i);
    ushort4 o;
    o.x = f2bf(v.x); o.y = f2bf(v.y); o.z = f2bf(v.z); o.w = f2bf(v.w);
    *(ushort4*)(xb + i) = o;
}

// Vb[p][i] = bf16(W[p&255][p>>8][i])  (row permutation fused into the pack)
__global__ void cvt_w_kernel(const float* __restrict__ W, unsigned short* __restrict__ vb) {
    int bid = blockIdx.x;
    int p   = bid >> 1;
    int i0  = (bid & 1) * 1024 + threadIdx.x * 4;
    int src = (p & (O_DIM - 1)) * (N_BINS * K_DIM) + (p >> 8) * K_DIM + i0;
    float4 v = *(const float4*)(W + src);
    ushort4 o;
    o.x = f2bf(v.x); o.y = f2bf(v.y); o.z = f2bf(v.z); o.w = f2bf(v.w);
    *(ushort4*)(vb + (size_t)p * K_DIM + i0) = o;
}

__device__ __forceinline__ u16x8 pack8(float4 a, float4 b) {
    u16x8 r;
    r[0] = f2bf(a.x); r[1] = f2bf(a.y); r[2] = f2bf(a.z); r[3] = f2bf(a.w);
    r[4] = f2bf(b.x); r[5] = f2bf(b.y); r[6] = f2bf(b.z); r[7] = f2bf(b.w);
    return r;
}

// ---- 256x256 quad-buffered BK=32 GEMM, cross-kt reg double-buffer ------
#define GLDS(gsrc, ldst) \
    __builtin_amdgcn_global_load_lds((const __attribute__((address_space(1))) void*)(gsrc), \
                                     (__attribute__((address_space(3))) void*)(ldst), 16, 0, 0)
#define SBAR()   __builtin_amdgcn_s_barrier()
#define WAIT_VM(N) do { asm volatile("s_waitcnt vmcnt(" #N ")" ::: "memory"); } while (0)
#define MFMA(a, b, c) (c) = __builtin_amdgcn_mfma_f32_16x16x32_bf16((a), (b), (c), 0, 0, 0)

// One K-tile, compile-time U (buffer = U&3, reg set S = U&1).
// Entry invariant (post-barrier): buf[U] and buf[U+1] collectively valid;
// fa[S]/fb[S] hold kt's m0-3 + b fragments (prefetched last iteration).
// PF: prefetch kt+1 frags into set S^1.  DO_STAGE: stage kt+3 -> buf[U+3].
#define ITER_BODY(U, PF, DO_STAGE, STAGE_KT, VMN) do {                                  \
    constexpr int S_ = (U) & 1;                                                         \
    constexpr int NU_ = ((U) + 1) & 3;                                                  \
    if (PF) {                                                                           \
        _Pragma("unroll") for (int m_ = 0; m_ < 4; ++m_)                                \
            fa[S_ ^ 1][m_] = *(const bf16x8*)&As[NU_][arb + m_ * 16][slot];             \
        _Pragma("unroll") for (int n_ = 0; n_ < 4; ++n_)                                \
            fb[S_ ^ 1][n_] = *(const bf16x8*)&Bs[NU_][brb + n_ * 16][slot];             \
    }                                                                                   \
    _Pragma("unroll") for (int m_ = 0; m_ < 4; ++m_)                                    \
        fa1[m_] = *(const bf16x8*)&As[(U) & 3][arb + 64 + m_ * 16][slot];               \
    if (DO_STAGE) stageA((STAGE_KT), ((U) + 3) & 3);                                    \
    __builtin_amdgcn_s_setprio(1);                                                      \
    _Pragma("unroll") for (int m_ = 0; m_ < 4; ++m_) {                                  \
        MFMA(fa[S_][m_], fb[S_][0], acc[m_][0]); MFMA(fa[S_][m_], fb[S_][1], acc[m_][1]); \
        MFMA(fa[S_][m_], fb[S_][2], acc[m_][2]); MFMA(fa[S_][m_], fb[S_][3], acc[m_][3]); \
    }                                                                                   \
    __builtin_amdgcn_s_setprio(0);                                                      \
    if (DO_STAGE) stageB((STAGE_KT), ((U) + 3) & 3);                                    \
    __builtin_amdgcn_s_setprio(1);                                                      \
    _Pragma("unroll") for (int m_ = 0; m_ < 4; ++m_) {                                  \
        MFMA(fa1[m_], fb[S_][0], acc[4 + m_][0]); MFMA(fa1[m_], fb[S_][1], acc[4 + m_][1]); \
        MFMA(fa1[m_], fb[S_][2], acc[4 + m_][2]); MFMA(fa1[m_], fb[S_][3], acc[4 + m_][3]); \
    }                                                                                   \
    __builtin_amdgcn_s_setprio(0);                                                      \
    WAIT_VM(VMN); SBAR();                                                               \
} while (0)

__global__ __launch_bounds__(512, 2) void gemm8_kernel(
    const unsigned short* __restrict__ xb,
    const unsigned short* __restrict__ vb,
    const float* __restrict__ bias,
    float* __restrict__ logits)
{
    // 4 buffers x [256 rows][32 K-elems] per operand; 4 x 16 KB x 2 = 128 KB
    __shared__ unsigned short As[4][256][32];
    __shared__ unsigned short Bs[4][256][32];

    const int tid  = threadIdx.x;
    const int lane = tid & 63;
    const int wv   = tid >> 6;
    const int wr   = wv >> 2;      // 0..1 -> A rows wr*128..+127
    const int wc   = wv & 3;       // 0..3 -> B cols wc*64..+63

    const int bid = blockIdx.x;
    // XCD swizzle (2048 blocks, %8==0 -> bijective)
    const int swz  = (bid & 7) * 256 + (bid >> 3);
    const int bm   = (swz >> 8) * 4 + (swz & 3);   // 0..31
    const int bn   = (swz & 255) >> 2;             // 0..63
    const int row0 = bm * 256;
    const int col0 = bn * 256;

    // staging source coords with inverse-swizzle (involution: byte ^= ((byte>>9)&1)<<5)
    const int oss = (tid * 16) ^ (tid & 32);
    const int sr  = oss >> 6;                  // row 0..127 within 8 KB chunk
    const int sc  = (oss >> 1) & 31;           // K-elem 0..31 (multiple of 8)

    const unsigned short* gA = xb + (size_t)(row0 + sr) * K_DIM + sc;
    const unsigned short* gB = vb + (size_t)(col0 + sr) * K_DIM + sc;

    auto stageA = [&](int k, int b) {
        const unsigned short* g = gA + k * 32;
        unsigned short* l = &As[b][0][0] + wv * 512;
        GLDS(g, l);
        GLDS(g + (size_t)128 * K_DIM, l + 4096);
    };
    auto stageB = [&](int k, int b) {
        const unsigned short* g = gB + k * 32;
        unsigned short* l = &Bs[b][0][0] + wv * 512;
        GLDS(g, l);
        GLDS(g + (size_t)128 * K_DIM, l + 4096);
    };

    // fragment read coords; swizzled slot (elem ^16 when lane&8, matching involution)
    const int arb  = wr * 128 + (lane & 15);
    const int brb  = wc * 64 + (lane & 15);
    const int slot = ((lane >> 4) * 8) ^ ((lane & 8) << 1);

    f32x4 acc[8][4];
#pragma unroll
    for (int m = 0; m < 8; ++m)
#pragma unroll
        for (int n = 0; n < 4; ++n)
            acc[m][n] = (f32x4){0.f, 0.f, 0.f, 0.f};

    bf16x8 fa[2][4], fb[2][4], fa1[4];

    // prologue: stage kt 0,1,2 (12 GLDS); vm(4) -> kt0,kt1 resident collectively
    stageA(0, 0); stageB(0, 0);
    stageA(1, 1); stageB(1, 1);
    stageA(2, 2); stageB(2, 2);
    WAIT_VM(4); SBAR();

    // preload set0 with kt0's m0-3 + b fragments
#pragma unroll
    for (int m = 0; m < 4; ++m) fa[0][m] = *(const bf16x8*)&As[0][arb + m * 16][slot];
#pragma unroll
    for (int n = 0; n < 4; ++n) fb[0][n] = *(const bf16x8*)&Bs[0][brb + n * 16][slot];

    // main loop: kt = 0..59, stage kt+3 (3..62), one vm(4)+barrier per kt
    for (int it = 0; it < 15; ++it) {
        const int kt0 = it * 4;
        ITER_BODY(0, 1, 1, kt0 + 3, 4);
        ITER_BODY(1, 1, 1, kt0 + 4, 4);
        ITER_BODY(2, 1, 1, kt0 + 5, 4);
        ITER_BODY(3, 1, 1, kt0 + 6, 4);
    }
    // tail: kt60 stages kt63; then drain
    ITER_BODY(0, 1, 1, 63, 4);   // kt60: vm(4) -> stage61,62 resident
    ITER_BODY(1, 1, 0, 0, 0);    // kt61: vm(0) -> stage63 resident
    ITER_BODY(2, 1, 0, 0, 0);    // kt62: prefetches buf3 (kt63) into set1
    // kt63 (peeled: no prefetch, no stage, no trailing barrier)
    {
#pragma unroll
        for (int m = 0; m < 4; ++m) fa1[m] = *(const bf16x8*)&As[3][arb + 64 + m * 16][slot];
        __builtin_amdgcn_s_setprio(1);
#pragma unroll
        for (int m = 0; m < 4; ++m) {
            MFMA(fa[1][m], fb[1][0], acc[m][0]); MFMA(fa[1][m], fb[1][1], acc[m][1]);
            MFMA(fa[1][m], fb[1][2], acc[m][2]); MFMA(fa[1][m], fb[1][3], acc[m][3]);
        }
#pragma unroll
        for (int m = 0; m < 4; ++m) {
            MFMA(fa1[m], fb[1][0], acc[4 + m][0]); MFMA(fa1[m], fb[1][1], acc[4 + m][1]);
            MFMA(fa1[m], fb[1][2], acc[4 + m][2]); MFMA(fa1[m], fb[1][3], acc[4 + m][3]);
        }
        __builtin_amdgcn_s_setprio(0);
    }

    // epilogue: C/D layout col = lane&15, row = (lane>>4)*4 + q
    const int r_base = row0 + wr * 128 + (lane >> 4) * 4;
    const int c_base = col0 + wc * 64 + (lane & 15);
#pragma unroll
    for (int n = 0; n < 4; ++n) {
        const int c = c_base + n * 16;
        const float bv = bias[(c & (O_DIM - 1)) * N_BINS + (c >> 8)];
#pragma unroll
        for (int m = 0; m < 8; ++m) {
            const int r = r_base + m * 16;
            float* out = logits + (size_t)r * J_DIM + c;
#pragma unroll
            for (int q = 0; q < 4; ++q)
                out[(size_t)q * J_DIM] = acc[m][n][q] + bv;
        }
    }
}

// ---- fallback GEMM (ws too small): 128x128, on-the-fly bf16 pack -------
__global__ __launch_bounds__(256) void gemm_fb(
    const float* __restrict__ xf,
    const float* __restrict__ Wf,
    const float* __restrict__ bias,
    float* __restrict__ logits)
{
    __shared__ unsigned short Asm_[128 * 32];
    __shared__ unsigned short Bsm_[128 * 32];

    const int tid = threadIdx.x;
    const int bid = blockIdx.x;
    const int swz = (bid & 7) * 1024 + (bid >> 3);
    const int row0 = (swz >> 7) * 128;
    const int col0 = (swz & 127) * 128;

    const int lane = tid & 63;
    const int wid  = tid >> 6;
    const int wr   = wid >> 1;
    const int wc   = wid & 1;

    f32x4 acc[4][4];
#pragma unroll
    for (int m = 0; m < 4; ++m)
#pragma unroll
        for (int n = 0; n < 4; ++n)
            acc[m][n] = (f32x4){0.f, 0.f, 0.f, 0.f};

    const int srow = tid >> 2;
    const int koff = (tid & 3) * 8;
    const int ra0 = row0 + srow, ra1 = row0 + 64 + srow;
    const int rb0 = col0 + srow, rb1 = col0 + 64 + srow;

    unsigned short* la0 = &Asm_[tid * 8];
    unsigned short* la1 = &Asm_[(256 + tid) * 8];
    unsigned short* lb0 = &Bsm_[tid * 8];
    unsigned short* lb1 = &Bsm_[(256 + tid) * 8];

    const float* fa0 = xf + (size_t)ra0 * K_DIM + koff;
    const float* fa1 = xf + (size_t)ra1 * K_DIM + koff;
    const float* fb0 = Wf + (size_t)((rb0 & (O_DIM - 1)) * (N_BINS * K_DIM) + (rb0 >> 8) * K_DIM) + koff;
    const float* fb1 = Wf + (size_t)((rb1 & (O_DIM - 1)) * (N_BINS * K_DIM) + (rb1 >> 8) * K_DIM) + koff;

    const int a_row  = wr * 64 + (lane & 15);
    const int b_row  = wc * 64 + (lane & 15);
    const int k_half = (lane >> 4) * 8;

    for (int kt = 0; kt < K_DIM / 32; ++kt) {
        const int kbase = kt * 32;
        *(u16x8*)la0 = pack8(*(const float4*)(fa0 + kbase), *(const float4*)(fa0 + kbase + 4));
        *(u16x8*)la1 = pack8(*(const float4*)(fa1 + kbase), *(const float4*)(fa1 + kbase + 4));
        *(u16x8*)lb0 = pack8(*(const float4*)(fb0 + kbase), *(const float4*)(fb0 + kbase + 4));
        *(u16x8*)lb1 = pack8(*(const float4*)(fb1 + kbase), *(const float4*)(fb1 + kbase + 4));
        __syncthreads();
        bf16x8 af[4], bg[4];
#pragma unroll
        for (int m = 0; m < 4; ++m) af[m] = *(const bf16x8*)&Asm_[(a_row + m * 16) * 32 + k_half];
#pragma unroll
        for (int n = 0; n < 4; ++n) bg[n] = *(const bf16x8*)&Bsm_[(b_row + n * 16) * 32 + k_half];
#pragma unroll
        for (int m = 0; m < 4; ++m)
#pragma unroll
            for (int n = 0; n < 4; ++n)
                MFMA(af[m], bg[n], acc[m][n]);
        __syncthreads();
    }

    const int r_base = row0 + wr * 64 + (lane >> 4) * 4;
    const int c_base = col0 + wc * 64 + (lane & 15);
#pragma unroll
    for (int n = 0; n < 4; ++n) {
        const int c = c_base + n * 16;
        const float bv = bias[(c & (O_DIM - 1)) * N_BINS + (c >> 8)];
#pragma unroll
        for (int m = 0; m < 4; ++m) {
            const int r = r_base + m * 16;
            float* out = logits + (size_t)r * J_DIM + c;
#pragma unroll
            for (int q = 0; q < 4; ++q)
                out[(size_t)q * J_DIM] = acc[m][n][q] + bv;
        }
    }
}

// ---- gumbel-softmax + grid dot ----------------------------------------
__global__ void softmax_encode_kernel(
    const float* __restrict__ logits,
    const float* __restrict__ gumbel,
    const float* __restrict__ grid,
    float* __restrict__ encoded)
{
    int t = blockIdx.x * 256 + threadIdx.x;
    int g = t >> 4;
    int l = t & 15;
    size_t base = (size_t)g * 64 + l * 4;
    float4 L = *(const float4*)(logits + base);
    float4 G = *(const float4*)(gumbel + base);
    float4 gr = *(const float4*)(grid + l * 4);

    float z0 = (L.x + G.x) * 2.0f;
    float z1 = (L.y + G.y) * 2.0f;
    float z2 = (L.z + G.z) * 2.0f;
    float z3 = (L.w + G.w) * 2.0f;

    float m = fmaxf(fmaxf(z0, z1), fmaxf(z2, z3));
#pragma unroll
    for (int s = 1; s < 16; s <<= 1) m = fmaxf(m, __shfl_xor(m, s, 16));

    float e0 = __expf(z0 - m), e1 = __expf(z1 - m), e2 = __expf(z2 - m), e3 = __expf(z3 - m);
    float ssum = e0 + e1 + e2 + e3;
    float dsum = e0 * gr.x + e1 * gr.y + e2 * gr.z + e3 * gr.w;
#pragma unroll
    for (int s = 1; s < 16; s <<= 1) {
        ssum += __shfl_xor(ssum, s, 16);
        dsum += __shfl_xor(dsum, s, 16);
    }
    if (l == 0) encoded[g] = dsum / ssum;
}

// ---- launch -------------------------------------------------------------
extern "C" void kernel_launch(void* const* d_in, const int* in_sizes, int n_in,
                              void* d_out, int out_size, void* d_ws, size_t ws_size,
                              hipStream_t stream) {
    const float* x      = (const float*)d_in[0];
    const float* W      = (const float*)d_in[1];
    const float* bias   = (const float*)d_in[2];
    const float* grid   = (const float*)d_in[3];
    const float* gumbel = (const float*)d_in[4];

    float* encoded = (float*)d_out;                           // [8192][256]
    float* logits  = (float*)d_out + (size_t)B_ROWS * O_DIM;  // [8192][16384]

    const size_t xb_bytes = (size_t)B_ROWS * K_DIM * 2;   // 32 MiB
    const size_t vb_bytes = (size_t)J_DIM * K_DIM * 2;    // 64 MiB

    if (ws_size >= xb_bytes + vb_bytes) {
        unsigned short* xb = (unsigned short*)d_ws;
        unsigned short* vb = (unsigned short*)((char*)d_ws + xb_bytes);
        cvt_x_kernel<<<(B_ROWS * K_DIM) / 1024, 256, 0, stream>>>(x, xb);
        cvt_w_kernel<<<J_DIM * 2, 256, 0, stream>>>(W, vb);
        gemm8_kernel<<<(B_ROWS / 256) * (J_DIM / 256), 512, 0, stream>>>(xb, vb, bias, logits);
    } else {
        gemm_fb<<<(B_ROWS / 128) * (J_DIM / 128), 256, 0, stream>>>(x, W, bias, logits);
    }

    softmax_encode_kernel<<<(B_ROWS * O_DIM * 16) / 256, 256, 0, stream>>>(logits, gumbel, grid, encoded);
}

// Round 5
// 823.285 us; speedup vs baseline: 1.0418x; 1.0418x over previous
//
#include <hip/hip_runtime.h>
#include <hip/hip_bf16.h>
#include <stdint.h>

typedef __bf16 bf16x8 __attribute__((ext_vector_type(8)));
typedef float f32x4 __attribute__((ext_vector_type(4)));
typedef unsigned short u16x8 __attribute__((ext_vector_type(8)));

#define B_ROWS 8192
#define K_DIM  2048
#define O_DIM  256
#define N_BINS 64
#define J_DIM  (O_DIM * N_BINS)   // 16384

__device__ __forceinline__ unsigned short f2bf(float f) {
    union { float f; unsigned u; } v; v.f = f;
    unsigned r = (v.u + 0x7fffu + ((v.u >> 16) & 1u)) >> 16;
    return (unsigned short)r;
}

// ---- conversion kernels ------------------------------------------------
__global__ void cvt_x_kernel(const float* __restrict__ x, unsigned short* __restrict__ xb) {
    int i = (blockIdx.x * 256 + threadIdx.x) * 4;
    float4 v = *(const float4*)(x + i);
    ushort4 o;
    o.x = f2bf(v.x); o.y = f2bf(v.y); o.z = f2bf(v.z); o.w = f2bf(v.w);
    *(ushort4*)(xb + i) = o;
}

// Vb[p][i] = bf16(W[p&255][p>>8][i])  (row permutation fused into the pack)
__global__ void cvt_w_kernel(const float* __restrict__ W, unsigned short* __restrict__ vb) {
    int bid = blockIdx.x;
    int p   = bid >> 1;
    int i0  = (bid & 1) * 1024 + threadIdx.x * 4;
    int src = (p & (O_DIM - 1)) * (N_BINS * K_DIM) + (p >> 8) * K_DIM + i0;
    float4 v = *(const float4*)(W + src);
    ushort4 o;
    o.x = f2bf(v.x); o.y = f2bf(v.y); o.z = f2bf(v.z); o.w = f2bf(v.w);
    *(ushort4*)(vb + (size_t)p * K_DIM + i0) = o;
}

__device__ __forceinline__ u16x8 pack8(float4 a, float4 b) {
    u16x8 r;
    r[0] = f2bf(a.x); r[1] = f2bf(a.y); r[2] = f2bf(a.z); r[3] = f2bf(a.w);
    r[4] = f2bf(b.x); r[5] = f2bf(b.y); r[6] = f2bf(b.z); r[7] = f2bf(b.w);
    return r;
}

// ---- 256x256 quad-buffered BK=32 GEMM (R3-verified loop) + fused epilogue
#define GLDS(gsrc, ldst) \
    __builtin_amdgcn_global_load_lds((const __attribute__((address_space(1))) void*)(gsrc), \
                                     (__attribute__((address_space(3))) void*)(ldst), 16, 0, 0)
#define SBAR()   __builtin_amdgcn_s_barrier()
#define SCHED0() __builtin_amdgcn_sched_barrier(0)
#define WAIT_VM(N)   do { asm volatile("s_waitcnt vmcnt(" #N ")" ::: "memory"); } while (0)
#define WAIT_LGKM(N) do { asm volatile("s_waitcnt lgkmcnt(" #N ")" ::: "memory"); SCHED0(); } while (0)
#define MFMA(a, b, c) (c) = __builtin_amdgcn_mfma_f32_16x16x32_bf16((a), (b), (c), 0, 0, 0)

// One K-tile: ph0 = m0-3 x n0-3 (16 MFMA), ph1 = m4-7 x n0-3 (16 MFMA).
#define KTILE_BODY(BUF, STAGE_A, STAGE_B) do {                                          \
    bf16x8 a0_[4], a1_[4], bf_[4];                                                      \
    _Pragma("unroll") for (int m_ = 0; m_ < 4; ++m_)                                    \
        a0_[m_] = *(const bf16x8*)&As[BUF][arb + m_ * 16][slot];                        \
    _Pragma("unroll") for (int n_ = 0; n_ < 4; ++n_)                                    \
        bf_[n_] = *(const bf16x8*)&Bs[BUF][brb + n_ * 16][slot];                        \
    _Pragma("unroll") for (int m_ = 0; m_ < 4; ++m_)                                    \
        a1_[m_] = *(const bf16x8*)&As[BUF][arb + 64 + m_ * 16][slot];                   \
    STAGE_A;                                                                            \
    WAIT_LGKM(4);                                                                       \
    __builtin_amdgcn_s_setprio(1);                                                      \
    _Pragma("unroll") for (int m_ = 0; m_ < 4; ++m_) {                                  \
        MFMA(a0_[m_], bf_[0], acc[m_][0]); MFMA(a0_[m_], bf_[1], acc[m_][1]);           \
        MFMA(a0_[m_], bf_[2], acc[m_][2]); MFMA(a0_[m_], bf_[3], acc[m_][3]);           \
    }                                                                                   \
    __builtin_amdgcn_s_setprio(0);                                                      \
    STAGE_B;                                                                            \
    WAIT_LGKM(0);                                                                       \
    __builtin_amdgcn_s_setprio(1);                                                      \
    _Pragma("unroll") for (int m_ = 0; m_ < 4; ++m_) {                                  \
        MFMA(a1_[m_], bf_[0], acc[4 + m_][0]); MFMA(a1_[m_], bf_[1], acc[4 + m_][1]);   \
        MFMA(a1_[m_], bf_[2], acc[4 + m_][2]); MFMA(a1_[m_], bf_[3], acc[4 + m_][3]);   \
    }                                                                                   \
    __builtin_amdgcn_s_setprio(0);                                                      \
} while (0)

__global__ __launch_bounds__(512, 2) void gemm8_kernel(
    const unsigned short* __restrict__ xb,
    const unsigned short* __restrict__ vb,
    const float* __restrict__ bias,
    const float* __restrict__ grid,
    const float* __restrict__ gumbel,
    float* __restrict__ logits,
    float* __restrict__ encoded)
{
    // 4 buffers x [256 rows][32 K-elems] per operand; 4 x 16 KB x 2 = 128 KB
    __shared__ unsigned short As[4][256][32];
    __shared__ unsigned short Bs[4][256][32];

    const int tid  = threadIdx.x;
    const int lane = tid & 63;
    const int wv   = tid >> 6;
    const int wr   = wv >> 2;      // 0..1 -> A rows wr*128..+127
    const int wc   = wv & 3;       // 0..3 -> B cols wc*64..+63

    const int bid = blockIdx.x;
    // XCD swizzle (2048 blocks, %8==0 -> bijective)
    const int swz  = (bid & 7) * 256 + (bid >> 3);
    const int bm   = (swz >> 8) * 4 + (swz & 3);   // 0..31
    const int bn   = (swz & 255) >> 2;             // 0..63
    const int row0 = bm * 256;
    const int col0 = bn * 256;

    // staging source coords with inverse-swizzle (involution: byte ^= ((byte>>9)&1)<<5)
    const int oss = (tid * 16) ^ (tid & 32);
    const int sr  = oss >> 6;                  // row 0..127 within 8 KB chunk
    const int sc  = (oss >> 1) & 31;           // K-elem 0..31 (multiple of 8)

    const unsigned short* gA = xb + (size_t)(row0 + sr) * K_DIM + sc;
    const unsigned short* gB = vb + (size_t)(col0 + sr) * K_DIM + sc;

    auto stageA = [&](int k, int b) {
        const unsigned short* g = gA + k * 32;
        unsigned short* l = &As[b][0][0] + wv * 512;
        GLDS(g, l);
        GLDS(g + (size_t)128 * K_DIM, l + 4096);
    };
    auto stageB = [&](int k, int b) {
        const unsigned short* g = gB + k * 32;
        unsigned short* l = &Bs[b][0][0] + wv * 512;
        GLDS(g, l);
        GLDS(g + (size_t)128 * K_DIM, l + 4096);
    };

    // fragment read coords; swizzled slot (elem ^16 when lane&8, matching involution)
    const int arb  = wr * 128 + (lane & 15);
    const int brb  = wc * 64 + (lane & 15);
    const int slot = ((lane >> 4) * 8) ^ ((lane & 8) << 1);

    f32x4 acc[8][4];
#pragma unroll
    for (int m = 0; m < 8; ++m)
#pragma unroll
        for (int n = 0; n < 4; ++n)
            acc[m][n] = (f32x4){0.f, 0.f, 0.f, 0.f};

    // prologue: stage K-tiles 0,1,2 (12 GLDS in flight)
    stageA(0, 0); stageB(0, 0);
    stageA(1, 1); stageB(1, 1);
    stageA(2, 2); stageB(2, 2);

    // main loop: kt = 0..59; stage kt+3 (up to 62); one vmcnt+barrier per K-tile
    for (int it = 0; it < 15; ++it) {
        const int kt0 = it * 4;
#pragma unroll
        for (int u = 0; u < 4; ++u) {
            WAIT_VM(8); SBAR();
            KTILE_BODY(u, stageA(kt0 + u + 3, (u + 3) & 3), stageB(kt0 + u + 3, (u + 3) & 3));
        }
    }
    // tail: kt = 60..63 (stage 63 at kt=60; drain 8/8/4/0)
    WAIT_VM(8); SBAR(); KTILE_BODY(0, stageA(63, 3), stageB(63, 3));
    WAIT_VM(8); SBAR(); KTILE_BODY(1, (void)0, (void)0);
    WAIT_VM(4); SBAR(); KTILE_BODY(2, (void)0, (void)0);
    WAIT_VM(0); SBAR(); KTILE_BODY(3, (void)0, (void)0);

    // ---- fused epilogue: logits store + gumbel-softmax + grid dot ----
    // C/D layout: col = lane&15 (+n*16), row = (lane>>4)*4 + q (+m*16)
    // wave's 64 cols = bins 0..63 of output feature o = col0/64 + wc
    const int lane15 = lane & 15;
    const int r_base = row0 + wr * 128 + (lane >> 4) * 4;
    const int o      = (col0 >> 6) + wc;
    const int c_base = col0 + wc * 64 + lane15;

    float gridv[4], biasv[4];
#pragma unroll
    for (int n = 0; n < 4; ++n) {
        gridv[n] = grid[n * 16 + lane15];
        const int c = c_base + n * 16;
        biasv[n] = bias[(c & (O_DIM - 1)) * N_BINS + (c >> 8)];
    }

#pragma unroll
    for (int m = 0; m < 8; ++m) {
#pragma unroll
        for (int q = 0; q < 4; ++q) {
            const int r = r_base + m * 16 + q;
            const size_t rowoff = (size_t)r * J_DIM + c_base;
            float lg[4], z[4];
            float gmax = -3.0e38f;
#pragma unroll
            for (int n = 0; n < 4; ++n) {
                lg[n] = acc[m][n][q] + biasv[n];
                const float gum = gumbel[rowoff + n * 16];
                z[n] = (lg[n] + gum) * 2.0f;   // / TAU, TAU = 0.5
                gmax = fmaxf(gmax, z[n]);
            }
#pragma unroll
            for (int n = 0; n < 4; ++n)
                logits[rowoff + n * 16] = lg[n];
            // row max across the 16-lane group (each group owns one row)
#pragma unroll
            for (int s = 1; s < 16; s <<= 1) gmax = fmaxf(gmax, __shfl_xor(gmax, s));
            float ss = 0.f, ds = 0.f;
#pragma unroll
            for (int n = 0; n < 4; ++n) {
                const float e = __expf(z[n] - gmax);
                ss += e; ds += e * gridv[n];
            }
#pragma unroll
            for (int s = 1; s < 16; s <<= 1) {
                ss += __shfl_xor(ss, s);
                ds += __shfl_xor(ds, s);
            }
            if (lane15 == 0) encoded[(size_t)r * O_DIM + o] = ds / ss;
        }
    }
}

// ---- fallback GEMM (ws too small): 128x128, on-the-fly bf16 pack -------
__global__ __launch_bounds__(256) void gemm_fb(
    const float* __restrict__ xf,
    const float* __restrict__ Wf,
    const float* __restrict__ bias,
    float* __restrict__ logits)
{
    __shared__ unsigned short Asm_[128 * 32];
    __shared__ unsigned short Bsm_[128 * 32];

    const int tid = threadIdx.x;
    const int bid = blockIdx.x;
    const int swz = (bid & 7) * 1024 + (bid >> 3);
    const int row0 = (swz >> 7) * 128;
    const int col0 = (swz & 127) * 128;

    const int lane = tid & 63;
    const int wid  = tid >> 6;
    const int wr   = wid >> 1;
    const int wc   = wid & 1;

    f32x4 acc[4][4];
#pragma unroll
    for (int m = 0; m < 4; ++m)
#pragma unroll
        for (int n = 0; n < 4; ++n)
            acc[m][n] = (f32x4){0.f, 0.f, 0.f, 0.f};

    const int srow = tid >> 2;
    const int koff = (tid & 3) * 8;
    const int ra0 = row0 + srow, ra1 = row0 + 64 + srow;
    const int rb0 = col0 + srow, rb1 = col0 + 64 + srow;

    unsigned short* la0 = &Asm_[tid * 8];
    unsigned short* la1 = &Asm_[(256 + tid) * 8];
    unsigned short* lb0 = &Bsm_[tid * 8];
    unsigned short* lb1 = &Bsm_[(256 + tid) * 8];

    const float* fa0 = xf + (size_t)ra0 * K_DIM + koff;
    const float* fa1 = xf + (size_t)ra1 * K_DIM + koff;
    const float* fb0 = Wf + (size_t)((rb0 & (O_DIM - 1)) * (N_BINS * K_DIM) + (rb0 >> 8) * K_DIM) + koff;
    const float* fb1 = Wf + (size_t)((rb1 & (O_DIM - 1)) * (N_BINS * K_DIM) + (rb1 >> 8) * K_DIM) + koff;

    const int a_row  = wr * 64 + (lane & 15);
    const int b_row  = wc * 64 + (lane & 15);
    const int k_half = (lane >> 4) * 8;

    for (int kt = 0; kt < K_DIM / 32; ++kt) {
        const int kbase = kt * 32;
        *(u16x8*)la0 = pack8(*(const float4*)(fa0 + kbase), *(const float4*)(fa0 + kbase + 4));
        *(u16x8*)la1 = pack8(*(const float4*)(fa1 + kbase), *(const float4*)(fa1 + kbase + 4));
        *(u16x8*)lb0 = pack8(*(const float4*)(fb0 + kbase), *(const float4*)(fb0 + kbase + 4));
        *(u16x8*)lb1 = pack8(*(const float4*)(fb1 + kbase), *(const float4*)(fb1 + kbase + 4));
        __syncthreads();
        bf16x8 af[4], bg[4];
#pragma unroll
        for (int m = 0; m < 4; ++m) af[m] = *(const bf16x8*)&Asm_[(a_row + m * 16) * 32 + k_half];
#pragma unroll
        for (int n = 0; n < 4; ++n) bg[n] = *(const bf16x8*)&Bsm_[(b_row + n * 16) * 32 + k_half];
#pragma unroll
        for (int m = 0; m < 4; ++m)
#pragma unroll
            for (int n = 0; n < 4; ++n)
                MFMA(af[m], bg[n], acc[m][n]);
        __syncthreads();
    }

    const int r_base = row0 + wr * 64 + (lane >> 4) * 4;
    const int c_base = col0 + wc * 64 + (lane & 15);
#pragma unroll
    for (int n = 0; n < 4; ++n) {
        const int c = c_base + n * 16;
        const float bv = bias[(c & (O_DIM - 1)) * N_BINS + (c >> 8)];
#pragma unroll
        for (int m = 0; m < 4; ++m) {
            const int r = r_base + m * 16;
            float* out = logits + (size_t)r * J_DIM + c;
#pragma unroll
            for (int q = 0; q < 4; ++q)
                out[(size_t)q * J_DIM] = acc[m][n][q] + bv;
        }
    }
}

// ---- standalone softmax (fallback path only) ---------------------------
__global__ void softmax_encode_kernel(
    const float* __restrict__ logits,
    const float* __restrict__ gumbel,
    const float* __restrict__ grid,
    float* __restrict__ encoded)
{
    int t = blockIdx.x * 256 + threadIdx.x;
    int g = t >> 4;
    int l = t & 15;
    size_t base = (size_t)g * 64 + l * 4;
    float4 L = *(const float4*)(logits + base);
    float4 G = *(const float4*)(gumbel + base);
    float4 gr = *(const float4*)(grid + l * 4);

    float z0 = (L.x + G.x) * 2.0f;
    float z1 = (L.y + G.y) * 2.0f;
    float z2 = (L.z + G.z) * 2.0f;
    float z3 = (L.w + G.w) * 2.0f;

    float m = fmaxf(fmaxf(z0, z1), fmaxf(z2, z3));
#pragma unroll
    for (int s = 1; s < 16; s <<= 1) m = fmaxf(m, __shfl_xor(m, s, 16));

    float e0 = __expf(z0 - m), e1 = __expf(z1 - m), e2 = __expf(z2 - m), e3 = __expf(z3 - m);
    float ssum = e0 + e1 + e2 + e3;
    float dsum = e0 * gr.x + e1 * gr.y + e2 * gr.z + e3 * gr.w;
#pragma unroll
    for (int s = 1; s < 16; s <<= 1) {
        ssum += __shfl_xor(ssum, s, 16);
        dsum += __shfl_xor(dsum, s, 16);
    }
    if (l == 0) encoded[g] = dsum / ssum;
}

// ---- launch -------------------------------------------------------------
extern "C" void kernel_launch(void* const* d_in, const int* in_sizes, int n_in,
                              void* d_out, int out_size, void* d_ws, size_t ws_size,
                              hipStream_t stream) {
    const float* x      = (const float*)d_in[0];
    const float* W      = (const float*)d_in[1];
    const float* bias   = (const float*)d_in[2];
    const float* grid   = (const float*)d_in[3];
    const float* gumbel = (const float*)d_in[4];

    float* encoded = (float*)d_out;                           // [8192][256]
    float* logits  = (float*)d_out + (size_t)B_ROWS * O_DIM;  // [8192][16384]

    const size_t xb_bytes = (size_t)B_ROWS * K_DIM * 2;   // 32 MiB
    const size_t vb_bytes = (size_t)J_DIM * K_DIM * 2;    // 64 MiB

    if (ws_size >= xb_bytes + vb_bytes) {
        unsigned short* xb = (unsigned short*)d_ws;
        unsigned short* vb = (unsigned short*)((char*)d_ws + xb_bytes);
        cvt_x_kernel<<<(B_ROWS * K_DIM) / 1024, 256, 0, stream>>>(x, xb);
        cvt_w_kernel<<<J_DIM * 2, 256, 0, stream>>>(W, vb);
        gemm8_kernel<<<(B_ROWS / 256) * (J_DIM / 256), 512, 0, stream>>>(
            xb, vb, bias, grid, gumbel, logits, encoded);
    } else {
        gemm_fb<<<(B_ROWS / 128) * (J_DIM / 128), 256, 0, stream>>>(x, W, bias, logits);
        softmax_encode_kernel<<<(B_ROWS * O_DIM * 16) / 256, 256, 0, stream>>>(logits, gumbel, grid, encoded);
    }
}

// Round 6
// 703.716 us; speedup vs baseline: 1.2188x; 1.1699x over previous
//
#include <hip/hip_runtime.h>
#include <hip/hip_bf16.h>
#include <stdint.h>

typedef __bf16 bf16x8 __attribute__((ext_vector_type(8)));
typedef float f32x4 __attribute__((ext_vector_type(4)));
typedef unsigned short u16x8 __attribute__((ext_vector_type(8)));

#define B_ROWS 8192
#define K_DIM  2048
#define O_DIM  256
#define N_BINS 64
#define J_DIM  (O_DIM * N_BINS)   // 16384

__device__ __forceinline__ unsigned short f2bf(float f) {
    union { float f; unsigned u; } v; v.f = f;
    unsigned r = (v.u + 0x7fffu + ((v.u >> 16) & 1u)) >> 16;
    return (unsigned short)r;
}

// ---- conversion kernels ------------------------------------------------
__global__ void cvt_x_kernel(const float* __restrict__ x, unsigned short* __restrict__ xb) {
    int i = (blockIdx.x * 256 + threadIdx.x) * 4;
    float4 v = *(const float4*)(x + i);
    ushort4 o;
    o.x = f2bf(v.x); o.y = f2bf(v.y); o.z = f2bf(v.z); o.w = f2bf(v.w);
    *(ushort4*)(xb + i) = o;
}

// Vb[p][i] = bf16(W[p&255][p>>8][i])  (row permutation fused into the pack)
__global__ void cvt_w_kernel(const float* __restrict__ W, unsigned short* __restrict__ vb) {
    int bid = blockIdx.x;
    int p   = bid >> 1;
    int i0  = (bid & 1) * 1024 + threadIdx.x * 4;
    int src = (p & (O_DIM - 1)) * (N_BINS * K_DIM) + (p >> 8) * K_DIM + i0;
    float4 v = *(const float4*)(W + src);
    ushort4 o;
    o.x = f2bf(v.x); o.y = f2bf(v.y); o.z = f2bf(v.z); o.w = f2bf(v.w);
    *(ushort4*)(vb + (size_t)p * K_DIM + i0) = o;
}

__device__ __forceinline__ u16x8 pack8(float4 a, float4 b) {
    u16x8 r;
    r[0] = f2bf(a.x); r[1] = f2bf(a.y); r[2] = f2bf(a.z); r[3] = f2bf(a.w);
    r[4] = f2bf(b.x); r[5] = f2bf(b.y); r[6] = f2bf(b.z); r[7] = f2bf(b.w);
    return r;
}

// ---- 256x256 quad-buffered BK=32 GEMM (R3-verified loop) + LDS-transposed epilogue
#define GLDS(gsrc, ldst) \
    __builtin_amdgcn_global_load_lds((const __attribute__((address_space(1))) void*)(gsrc), \
                                     (__attribute__((address_space(3))) void*)(ldst), 16, 0, 0)
#define SBAR()   __builtin_amdgcn_s_barrier()
#define SCHED0() __builtin_amdgcn_sched_barrier(0)
#define WAIT_VM(N)   do { asm volatile("s_waitcnt vmcnt(" #N ")" ::: "memory"); } while (0)
#define WAIT_LGKM(N) do { asm volatile("s_waitcnt lgkmcnt(" #N ")" ::: "memory"); SCHED0(); } while (0)
#define MFMA(a, b, c) (c) = __builtin_amdgcn_mfma_f32_16x16x32_bf16((a), (b), (c), 0, 0, 0)

// One K-tile: ph0 = m0-3 x n0-3 (16 MFMA), ph1 = m4-7 x n0-3 (16 MFMA).
#define KTILE_BODY(BUF, STAGE_A, STAGE_B) do {                                          \
    bf16x8 a0_[4], a1_[4], bf_[4];                                                      \
    _Pragma("unroll") for (int m_ = 0; m_ < 4; ++m_)                                    \
        a0_[m_] = *(const bf16x8*)&As[BUF][arb + m_ * 16][slot];                        \
    _Pragma("unroll") for (int n_ = 0; n_ < 4; ++n_)                                    \
        bf_[n_] = *(const bf16x8*)&Bs[BUF][brb + n_ * 16][slot];                        \
    _Pragma("unroll") for (int m_ = 0; m_ < 4; ++m_)                                    \
        a1_[m_] = *(const bf16x8*)&As[BUF][arb + 64 + m_ * 16][slot];                   \
    STAGE_A;                                                                            \
    WAIT_LGKM(4);                                                                       \
    __builtin_amdgcn_s_setprio(1);                                                      \
    _Pragma("unroll") for (int m_ = 0; m_ < 4; ++m_) {                                  \
        MFMA(a0_[m_], bf_[0], acc[m_][0]); MFMA(a0_[m_], bf_[1], acc[m_][1]);           \
        MFMA(a0_[m_], bf_[2], acc[m_][2]); MFMA(a0_[m_], bf_[3], acc[m_][3]);           \
    }                                                                                   \
    __builtin_amdgcn_s_setprio(0);                                                      \
    STAGE_B;                                                                            \
    WAIT_LGKM(0);                                                                       \
    __builtin_amdgcn_s_setprio(1);                                                      \
    _Pragma("unroll") for (int m_ = 0; m_ < 4; ++m_) {                                  \
        MFMA(a1_[m_], bf_[0], acc[4 + m_][0]); MFMA(a1_[m_], bf_[1], acc[4 + m_][1]);   \
        MFMA(a1_[m_], bf_[2], acc[4 + m_][2]); MFMA(a1_[m_], bf_[3], acc[4 + m_][3]);   \
    }                                                                                   \
    __builtin_amdgcn_s_setprio(0);                                                      \
} while (0)

__global__ __launch_bounds__(512, 2) void gemm8_kernel(
    const unsigned short* __restrict__ xb,
    const unsigned short* __restrict__ vb,
    const float* __restrict__ bias,
    const float* __restrict__ grid,
    const float* __restrict__ gumbel,
    float* __restrict__ logits,
    float* __restrict__ encoded)
{
    // one 128 KB pool: K-loop = As[4][256][32] + Bs[4][256][32];
    // epilogue aliases it as float[128][256] (exactly 131072 B)
    __shared__ __align__(16) unsigned char pool[131072];
    auto As = (unsigned short (*)[256][32])pool;
    auto Bs = (unsigned short (*)[256][32])(pool + 65536);
    float* ep = (float*)pool;

    const int tid  = threadIdx.x;
    const int lane = tid & 63;
    const int wv   = tid >> 6;
    const int wr   = wv >> 2;      // 0..1 -> A rows wr*128..+127
    const int wc   = wv & 3;       // 0..3 -> B cols wc*64..+63

    const int bid = blockIdx.x;
    // XCD swizzle (2048 blocks, %8==0 -> bijective)
    const int swz  = (bid & 7) * 256 + (bid >> 3);
    const int bm   = (swz >> 8) * 4 + (swz & 3);   // 0..31
    const int bn   = (swz & 255) >> 2;             // 0..63
    const int row0 = bm * 256;
    const int col0 = bn * 256;

    // staging source coords with inverse-swizzle (involution: byte ^= ((byte>>9)&1)<<5)
    const int oss = (tid * 16) ^ (tid & 32);
    const int sr  = oss >> 6;                  // row 0..127 within 8 KB chunk
    const int sc  = (oss >> 1) & 31;           // K-elem 0..31 (multiple of 8)

    const unsigned short* gA = xb + (size_t)(row0 + sr) * K_DIM + sc;
    const unsigned short* gB = vb + (size_t)(col0 + sr) * K_DIM + sc;

    auto stageA = [&](int k, int b) {
        const unsigned short* g = gA + k * 32;
        unsigned short* l = &As[b][0][0] + wv * 512;
        GLDS(g, l);
        GLDS(g + (size_t)128 * K_DIM, l + 4096);
    };
    auto stageB = [&](int k, int b) {
        const unsigned short* g = gB + k * 32;
        unsigned short* l = &Bs[b][0][0] + wv * 512;
        GLDS(g, l);
        GLDS(g + (size_t)128 * K_DIM, l + 4096);
    };

    // fragment read coords; swizzled slot (elem ^16 when lane&8, matching involution)
    const int arb  = wr * 128 + (lane & 15);
    const int brb  = wc * 64 + (lane & 15);
    const int slot = ((lane >> 4) * 8) ^ ((lane & 8) << 1);

    f32x4 acc[8][4];
#pragma unroll
    for (int m = 0; m < 8; ++m)
#pragma unroll
        for (int n = 0; n < 4; ++n)
            acc[m][n] = (f32x4){0.f, 0.f, 0.f, 0.f};

    // prologue: stage K-tiles 0,1,2 (12 GLDS in flight)
    stageA(0, 0); stageB(0, 0);
    stageA(1, 1); stageB(1, 1);
    stageA(2, 2); stageB(2, 2);

    // main loop: kt = 0..59; stage kt+3 (up to 62); one vmcnt+barrier per K-tile
    for (int it = 0; it < 15; ++it) {
        const int kt0 = it * 4;
#pragma unroll
        for (int u = 0; u < 4; ++u) {
            WAIT_VM(8); SBAR();
            KTILE_BODY(u, stageA(kt0 + u + 3, (u + 3) & 3), stageB(kt0 + u + 3, (u + 3) & 3));
        }
    }
    // tail: kt = 60..63 (stage 63 at kt=60; drain 8/8/4/0)
    WAIT_VM(8); SBAR(); KTILE_BODY(0, stageA(63, 3), stageB(63, 3));
    WAIT_VM(8); SBAR(); KTILE_BODY(1, (void)0, (void)0);
    WAIT_VM(4); SBAR(); KTILE_BODY(2, (void)0, (void)0);
    WAIT_VM(0); SBAR(); KTILE_BODY(3, (void)0, (void)0);

    SBAR();   // all waves' LDS reads done before epilogue reuses the pool

    // ---- fused epilogue via LDS transpose -------------------------------
    // C/D layout: col = lane&15 (+n*16), row = (lane>>4)*4 + q (+m*16)
    const int lane15 = lane & 15;
    const int hi4    = lane >> 4;

    float biasv[4];
#pragma unroll
    for (int n = 0; n < 4; ++n) {
        const int c = col0 + wc * 64 + n * 16 + lane15;
        biasv[n] = bias[(c & (O_DIM - 1)) * N_BINS + (c >> 8)];
    }
    // lane l owns bins l*4..l*4+3 in the compute phase
    const float4 gridv = *(const float4*)(grid + lane15 * 4);

#pragma unroll
    for (int h = 0; h < 2; ++h) {
        // write phase: waves with wr==h deposit their 128 rows x 64 cols (+bias)
        if (wr == h) {
#pragma unroll
            for (int m = 0; m < 8; ++m)
#pragma unroll
                for (int n = 0; n < 4; ++n) {
                    const int cd = wc * 64 + n * 16 + lane15;
#pragma unroll
                    for (int q = 0; q < 4; ++q) {
                        const int rl = m * 16 + hi4 * 4 + q;
                        ep[rl * 256 + (cd ^ ((rl & 7) << 2))] = acc[m][n][q] + biasv[n];
                    }
                }
        }
        SBAR();

        // compute phase: all 8 waves; wave handles rows i*8+wv, lanes cover
        // 256 consecutive dwords (1 KB) -> coalesced float4 global I/O
        const int cb = hi4 * 64 + lane15 * 4;                 // dword col base
        const float* gptr = gumbel + (size_t)(row0 + h * 128 + wv) * J_DIM + col0 + cb;
        float*       lptr = logits + (size_t)(row0 + h * 128 + wv) * J_DIM + col0 + cb;

        float4 gq[4];
#pragma unroll
        for (int p = 0; p < 4; ++p)
            gq[p] = *(const float4*)(gptr + (size_t)p * 8 * J_DIM);

#pragma unroll
        for (int i = 0; i < 16; ++i) {
            const int r = i * 8 + wv;
            const float4 L = *(const float4*)&ep[r * 256 + (cb ^ ((r & 7) << 2))];
            const float4 G = gq[i & 3];
            if (i < 12)
                gq[i & 3] = *(const float4*)(gptr + (size_t)(i + 4) * 8 * J_DIM);

            float z0 = (L.x + G.x) * 2.0f;   // / TAU, TAU = 0.5
            float z1 = (L.y + G.y) * 2.0f;
            float z2 = (L.z + G.z) * 2.0f;
            float z3 = (L.w + G.w) * 2.0f;
            float gmax = fmaxf(fmaxf(z0, z1), fmaxf(z2, z3));
#pragma unroll
            for (int s = 1; s < 16; s <<= 1) gmax = fmaxf(gmax, __shfl_xor(gmax, s));

            const float e0 = __expf(z0 - gmax), e1 = __expf(z1 - gmax);
            const float e2 = __expf(z2 - gmax), e3 = __expf(z3 - gmax);
            float ss = e0 + e1 + e2 + e3;
            float ds = e0 * gridv.x + e1 * gridv.y + e2 * gridv.z + e3 * gridv.w;
#pragma unroll
            for (int s = 1; s < 16; s <<= 1) {
                ss += __shfl_xor(ss, s);
                ds += __shfl_xor(ds, s);
            }

            *(float4*)(lptr + (size_t)i * 8 * J_DIM) = L;
            if (lane15 == 0)
                encoded[(size_t)(row0 + h * 128 + r) * O_DIM + (col0 >> 6) + hi4] = ds / ss;
        }
        SBAR();   // reads of this half done before next half's writes
    }
}

// ---- fallback GEMM (ws too small): 128x128, on-the-fly bf16 pack -------
__global__ __launch_bounds__(256) void gemm_fb(
    const float* __restrict__ xf,
    const float* __restrict__ Wf,
    const float* __restrict__ bias,
    float* __restrict__ logits)
{
    __shared__ unsigned short Asm_[128 * 32];
    __shared__ unsigned short Bsm_[128 * 32];

    const int tid = threadIdx.x;
    const int bid = blockIdx.x;
    const int swz = (bid & 7) * 1024 + (bid >> 3);
    const int row0 = (swz >> 7) * 128;
    const int col0 = (swz & 127) * 128;

    const int lane = tid & 63;
    const int wid  = tid >> 6;
    const int wr   = wid >> 1;
    const int wc   = wid & 1;

    f32x4 acc[4][4];
#pragma unroll
    for (int m = 0; m < 4; ++m)
#pragma unroll
        for (int n = 0; n < 4; ++n)
            acc[m][n] = (f32x4){0.f, 0.f, 0.f, 0.f};

    const int srow = tid >> 2;
    const int koff = (tid & 3) * 8;
    const int ra0 = row0 + srow, ra1 = row0 + 64 + srow;
    const int rb0 = col0 + srow, rb1 = col0 + 64 + srow;

    unsigned short* la0 = &Asm_[tid * 8];
    unsigned short* la1 = &Asm_[(256 + tid) * 8];
    unsigned short* lb0 = &Bsm_[tid * 8];
    unsigned short* lb1 = &Bsm_[(256 + tid) * 8];

    const float* fa0 = xf + (size_t)ra0 * K_DIM + koff;
    const float* fa1 = xf + (size_t)ra1 * K_DIM + koff;
    const float* fb0 = Wf + (size_t)((rb0 & (O_DIM - 1)) * (N_BINS * K_DIM) + (rb0 >> 8) * K_DIM) + koff;
    const float* fb1 = Wf + (size_t)((rb1 & (O_DIM - 1)) * (N_BINS * K_DIM) + (rb1 >> 8) * K_DIM) + koff;

    const int a_row  = wr * 64 + (lane & 15);
    const int b_row  = wc * 64 + (lane & 15);
    const int k_half = (lane >> 4) * 8;

    for (int kt = 0; kt < K_DIM / 32; ++kt) {
        const int kbase = kt * 32;
        *(u16x8*)la0 = pack8(*(const float4*)(fa0 + kbase), *(const float4*)(fa0 + kbase + 4));
        *(u16x8*)la1 = pack8(*(const float4*)(fa1 + kbase), *(const float4*)(fa1 + kbase + 4));
        *(u16x8*)lb0 = pack8(*(const float4*)(fb0 + kbase), *(const float4*)(fb0 + kbase + 4));
        *(u16x8*)lb1 = pack8(*(const float4*)(fb1 + kbase), *(const float4*)(fb1 + kbase + 4));
        __syncthreads();
        bf16x8 af[4], bg[4];
#pragma unroll
        for (int m = 0; m < 4; ++m) af[m] = *(const bf16x8*)&Asm_[(a_row + m * 16) * 32 + k_half];
#pragma unroll
        for (int n = 0; n < 4; ++n) bg[n] = *(const bf16x8*)&Bsm_[(b_row + n * 16) * 32 + k_half];
#pragma unroll
        for (int m = 0; m < 4; ++m)
#pragma unroll
            for (int n = 0; n < 4; ++n)
                MFMA(af[m], bg[n], acc[m][n]);
        __syncthreads();
    }

    const int r_base = row0 + wr * 64 + (lane >> 4) * 4;
    const int c_base = col0 + wc * 64 + (lane & 15);
#pragma unroll
    for (int n = 0; n < 4; ++n) {
        const int c = c_base + n * 16;
        const float bv = bias[(c & (O_DIM - 1)) * N_BINS + (c >> 8)];
#pragma unroll
        for (int m = 0; m < 4; ++m) {
            const int r = r_base + m * 16;
            float* out = logits + (size_t)r * J_DIM + c;
#pragma unroll
            for (int q = 0; q < 4; ++q)
                out[(size_t)q * J_DIM] = acc[m][n][q] + bv;
        }
    }
}

// ---- standalone softmax (fallback path only) ---------------------------
__global__ void softmax_encode_kernel(
    const float* __restrict__ logits,
    const float* __restrict__ gumbel,
    const float* __restrict__ grid,
    float* __restrict__ encoded)
{
    int t = blockIdx.x * 256 + threadIdx.x;
    int g = t >> 4;
    int l = t & 15;
    size_t base = (size_t)g * 64 + l * 4;
    float4 L = *(const float4*)(logits + base);
    float4 G = *(const float4*)(gumbel + base);
    float4 gr = *(const float4*)(grid + l * 4);

    float z0 = (L.x + G.x) * 2.0f;
    float z1 = (L.y + G.y) * 2.0f;
    float z2 = (L.z + G.z) * 2.0f;
    float z3 = (L.w + G.w) * 2.0f;

    float m = fmaxf(fmaxf(z0, z1), fmaxf(z2, z3));
#pragma unroll
    for (int s = 1; s < 16; s <<= 1) m = fmaxf(m, __shfl_xor(m, s, 16));

    float e0 = __expf(z0 - m), e1 = __expf(z1 - m), e2 = __expf(z2 - m), e3 = __expf(z3 - m);
    float ssum = e0 + e1 + e2 + e3;
    float dsum = e0 * gr.x + e1 * gr.y + e2 * gr.z + e3 * gr.w;
#pragma unroll
    for (int s = 1; s < 16; s <<= 1) {
        ssum += __shfl_xor(ssum, s, 16);
        dsum += __shfl_xor(dsum, s, 16);
    }
    if (l == 0) encoded[g] = dsum / ssum;
}

// ---- launch -------------------------------------------------------------
extern "C" void kernel_launch(void* const* d_in, const int* in_sizes, int n_in,
                              void* d_out, int out_size, void* d_ws, size_t ws_size,
                              hipStream_t stream) {
    const float* x      = (const float*)d_in[0];
    const float* W      = (const float*)d_in[1];
    const float* bias   = (const float*)d_in[2];
    const float* grid   = (const float*)d_in[3];
    const float* gumbel = (const float*)d_in[4];

    float* encoded = (float*)d_out;                           // [8192][256]
    float* logits  = (float*)d_out + (size_t)B_ROWS * O_DIM;  // [8192][16384]

    const size_t xb_bytes = (size_t)B_ROWS * K_DIM * 2;   // 32 MiB
    const size_t vb_bytes = (size_t)J_DIM * K_DIM * 2;    // 64 MiB

    if (ws_size >= xb_bytes + vb_bytes) {
        unsigned short* xb = (unsigned short*)d_ws;
        unsigned short* vb = (unsigned short*)((char*)d_ws + xb_bytes);
        cvt_x_kernel<<<(B_ROWS * K_DIM) / 1024, 256, 0, stream>>>(x, xb);
        cvt_w_kernel<<<J_DIM * 2, 256, 0, stream>>>(W, vb);
        gemm8_kernel<<<(B_ROWS / 256) * (J_DIM / 256), 512, 0, stream>>>(
            xb, vb, bias, grid, gumbel, logits, encoded);
    } else {
        gemm_fb<<<(B_ROWS / 128) * (J_DIM / 128), 256, 0, stream>>>(x, W, bias, logits);
        softmax_encode_kernel<<<(B_ROWS * O_DIM * 16) / 256, 256, 0, stream>>>(logits, gumbel, grid, encoded);
    }
}

// Round 7
// 700.404 us; speedup vs baseline: 1.2246x; 1.0047x over previous
//
#include <hip/hip_runtime.h>
#include <hip/hip_bf16.h>
#include <stdint.h>

typedef __bf16 bf16x8 __attribute__((ext_vector_type(8)));
typedef float f32x4 __attribute__((ext_vector_type(4)));
typedef unsigned short u16x8 __attribute__((ext_vector_type(8)));

#define B_ROWS 8192
#define K_DIM  2048
#define O_DIM  256
#define N_BINS 64
#define J_DIM  (O_DIM * N_BINS)   // 16384

__device__ __forceinline__ unsigned short f2bf(float f) {
    union { float f; unsigned u; } v; v.f = f;
    unsigned r = (v.u + 0x7fffu + ((v.u >> 16) & 1u)) >> 16;
    return (unsigned short)r;
}

// ---- conversion kernels ------------------------------------------------
__global__ void cvt_x_kernel(const float* __restrict__ x, unsigned short* __restrict__ xb) {
    int i = (blockIdx.x * 256 + threadIdx.x) * 4;
    float4 v = *(const float4*)(x + i);
    ushort4 o;
    o.x = f2bf(v.x); o.y = f2bf(v.y); o.z = f2bf(v.z); o.w = f2bf(v.w);
    *(ushort4*)(xb + i) = o;
}

// Vb[p][i] = bf16(W[p&255][p>>8][i])  (row permutation fused into the pack)
__global__ void cvt_w_kernel(const float* __restrict__ W, unsigned short* __restrict__ vb) {
    int bid = blockIdx.x;
    int p   = bid >> 1;
    int i0  = (bid & 1) * 1024 + threadIdx.x * 4;
    int src = (p & (O_DIM - 1)) * (N_BINS * K_DIM) + (p >> 8) * K_DIM + i0;
    float4 v = *(const float4*)(W + src);
    ushort4 o;
    o.x = f2bf(v.x); o.y = f2bf(v.y); o.z = f2bf(v.z); o.w = f2bf(v.w);
    *(ushort4*)(vb + (size_t)p * K_DIM + i0) = o;
}

__device__ __forceinline__ u16x8 pack8(float4 a, float4 b) {
    u16x8 r;
    r[0] = f2bf(a.x); r[1] = f2bf(a.y); r[2] = f2bf(a.z); r[3] = f2bf(a.w);
    r[4] = f2bf(b.x); r[5] = f2bf(b.y); r[6] = f2bf(b.z); r[7] = f2bf(b.w);
    return r;
}

// ---- 256x256 quad-buffered BK=32 GEMM + LDS-transposed fused epilogue --
#define GLDS(gsrc, ldst) \
    __builtin_amdgcn_global_load_lds((const __attribute__((address_space(1))) void*)(gsrc), \
                                     (__attribute__((address_space(3))) void*)(ldst), 16, 0, 0)
#define SBAR()   __builtin_amdgcn_s_barrier()
#define WAIT_VM(N) do { asm volatile("s_waitcnt vmcnt(" #N ")" ::: "memory"); } while (0)
#define MFMA(a, b, c) (c) = __builtin_amdgcn_mfma_f32_16x16x32_bf16((a), (b), (c), 0, 0, 0)

// One K-tile: cluster1 = m0-3 x n0-3 (16 MFMA), cluster2 = m4-7 x n0-3.
// NO manual lgkm waits: ds_reads are compiler-visible loads, so hipcc emits
// fine-grained lgkmcnt per consuming MFMA (first MFMA gated on 2 loads, not 8).
#define KTILE_BODY(BUF, STAGE_A, STAGE_B) do {                                          \
    bf16x8 a0_[4], a1_[4], bf_[4];                                                      \
    _Pragma("unroll") for (int n_ = 0; n_ < 4; ++n_)                                    \
        bf_[n_] = *(const bf16x8*)&Bs[BUF][brb + n_ * 16][slot];                        \
    _Pragma("unroll") for (int m_ = 0; m_ < 4; ++m_)                                    \
        a0_[m_] = *(const bf16x8*)&As[BUF][arb + m_ * 16][slot];                        \
    STAGE_A;                                                                            \
    __builtin_amdgcn_s_setprio(1);                                                      \
    _Pragma("unroll") for (int m_ = 0; m_ < 4; ++m_) {                                  \
        MFMA(a0_[m_], bf_[0], acc[m_][0]); MFMA(a0_[m_], bf_[1], acc[m_][1]);           \
        MFMA(a0_[m_], bf_[2], acc[m_][2]); MFMA(a0_[m_], bf_[3], acc[m_][3]);           \
    }                                                                                   \
    __builtin_amdgcn_s_setprio(0);                                                      \
    _Pragma("unroll") for (int m_ = 0; m_ < 4; ++m_)                                    \
        a1_[m_] = *(const bf16x8*)&As[BUF][arb + 64 + m_ * 16][slot];                   \
    STAGE_B;                                                                            \
    __builtin_amdgcn_s_setprio(1);                                                      \
    _Pragma("unroll") for (int m_ = 0; m_ < 4; ++m_) {                                  \
        MFMA(a1_[m_], bf_[0], acc[4 + m_][0]); MFMA(a1_[m_], bf_[1], acc[4 + m_][1]);   \
        MFMA(a1_[m_], bf_[2], acc[4 + m_][2]); MFMA(a1_[m_], bf_[3], acc[4 + m_][3]);   \
    }                                                                                   \
    __builtin_amdgcn_s_setprio(0);                                                      \
} while (0)

__global__ __launch_bounds__(512, 2) void gemm8_kernel(
    const unsigned short* __restrict__ xb,
    const unsigned short* __restrict__ vb,
    const float* __restrict__ bias,
    const float* __restrict__ grid,
    const float* __restrict__ gumbel,
    float* __restrict__ logits,
    float* __restrict__ encoded)
{
    // one 128 KB pool: K-loop = As[4][256][32] + Bs[4][256][32];
    // epilogue aliases it as float[128][256] (exactly 131072 B)
    __shared__ __align__(16) unsigned char pool[131072];
    auto As = (unsigned short (*)[256][32])pool;
    auto Bs = (unsigned short (*)[256][32])(pool + 65536);
    float* ep = (float*)pool;

    const int tid  = threadIdx.x;
    const int lane = tid & 63;
    const int wv   = tid >> 6;
    const int wr   = wv >> 2;      // 0..1 -> A rows wr*128..+127
    const int wc   = wv & 3;       // 0..3 -> B cols wc*64..+63

    const int bid = blockIdx.x;
    // XCD swizzle (2048 blocks, %8==0 -> bijective)
    const int swz  = (bid & 7) * 256 + (bid >> 3);
    const int bm   = (swz >> 8) * 4 + (swz & 3);   // 0..31
    const int bn   = (swz & 255) >> 2;             // 0..63
    const int row0 = bm * 256;
    const int col0 = bn * 256;

    // staging source coords with inverse-swizzle (involution: byte ^= ((byte>>9)&1)<<5)
    const int oss = (tid * 16) ^ (tid & 32);
    const int sr  = oss >> 6;                  // row 0..127 within 8 KB chunk
    const int sc  = (oss >> 1) & 31;           // K-elem 0..31 (multiple of 8)

    const unsigned short* gA = xb + (size_t)(row0 + sr) * K_DIM + sc;
    const unsigned short* gB = vb + (size_t)(col0 + sr) * K_DIM + sc;

    auto stageA = [&](int k, int b) {
        const unsigned short* g = gA + k * 32;
        unsigned short* l = &As[b][0][0] + wv * 512;
        GLDS(g, l);
        GLDS(g + (size_t)128 * K_DIM, l + 4096);
    };
    auto stageB = [&](int k, int b) {
        const unsigned short* g = gB + k * 32;
        unsigned short* l = &Bs[b][0][0] + wv * 512;
        GLDS(g, l);
        GLDS(g + (size_t)128 * K_DIM, l + 4096);
    };

    // fragment read coords; swizzled slot (elem ^16 when lane&8, matching involution)
    const int arb  = wr * 128 + (lane & 15);
    const int brb  = wc * 64 + (lane & 15);
    const int slot = ((lane >> 4) * 8) ^ ((lane & 8) << 1);

    f32x4 acc[8][4];
#pragma unroll
    for (int m = 0; m < 8; ++m)
#pragma unroll
        for (int n = 0; n < 4; ++n)
            acc[m][n] = (f32x4){0.f, 0.f, 0.f, 0.f};

    // prologue: stage K-tiles 0,1,2 (12 GLDS in flight)
    stageA(0, 0); stageB(0, 0);
    stageA(1, 1); stageB(1, 1);
    stageA(2, 2); stageB(2, 2);

    // main loop: kt = 0..59; stage kt+3 (up to 62); one vmcnt+barrier per K-tile
    for (int it = 0; it < 15; ++it) {
        const int kt0 = it * 4;
#pragma unroll
        for (int u = 0; u < 4; ++u) {
            WAIT_VM(8); SBAR();
            KTILE_BODY(u, stageA(kt0 + u + 3, (u + 3) & 3), stageB(kt0 + u + 3, (u + 3) & 3));
        }
    }
    // tail: kt = 60..63 (stage 63 at kt=60; drain 8/8/4/0)
    WAIT_VM(8); SBAR(); KTILE_BODY(0, stageA(63, 3), stageB(63, 3));
    WAIT_VM(8); SBAR(); KTILE_BODY(1, (void)0, (void)0);
    WAIT_VM(4); SBAR(); KTILE_BODY(2, (void)0, (void)0);
    WAIT_VM(0); SBAR(); KTILE_BODY(3, (void)0, (void)0);

    SBAR();   // all waves' LDS reads done before epilogue reuses the pool

    // ---- fused epilogue via LDS transpose -------------------------------
    // C/D layout: col = lane&15 (+n*16), row = (lane>>4)*4 + q (+m*16)
    const int lane15 = lane & 15;
    const int hi4    = lane >> 4;

    float biasv[4];
#pragma unroll
    for (int n = 0; n < 4; ++n) {
        const int c = col0 + wc * 64 + n * 16 + lane15;
        biasv[n] = bias[(c & (O_DIM - 1)) * N_BINS + (c >> 8)];
    }
    // lane l owns bins l*4..l*4+3 in the compute phase
    const float4 gridv = *(const float4*)(grid + lane15 * 4);

#pragma unroll
    for (int h = 0; h < 2; ++h) {
        // write phase: waves with wr==h deposit their 128 rows x 64 cols (+bias)
        if (wr == h) {
#pragma unroll
            for (int m = 0; m < 8; ++m)
#pragma unroll
                for (int n = 0; n < 4; ++n) {
                    const int cd = wc * 64 + n * 16 + lane15;
#pragma unroll
                    for (int q = 0; q < 4; ++q) {
                        const int rl = m * 16 + hi4 * 4 + q;
                        ep[rl * 256 + (cd ^ ((rl & 7) << 2))] = acc[m][n][q] + biasv[n];
                    }
                }
        }
        SBAR();

        // compute phase: all 8 waves; wave handles rows i*8+wv, lanes cover
        // 256 consecutive dwords (1 KB) -> coalesced float4 global I/O
        const int cb = hi4 * 64 + lane15 * 4;                 // dword col base
        const float* gptr = gumbel + (size_t)(row0 + h * 128 + wv) * J_DIM + col0 + cb;
        float*       lptr = logits + (size_t)(row0 + h * 128 + wv) * J_DIM + col0 + cb;

        float4 gq[4];
#pragma unroll
        for (int p = 0; p < 4; ++p)
            gq[p] = *(const float4*)(gptr + (size_t)p * 8 * J_DIM);

#pragma unroll
        for (int i = 0; i < 16; ++i) {
            const int r = i * 8 + wv;
            const float4 L = *(const float4*)&ep[r * 256 + (cb ^ ((r & 7) << 2))];
            const float4 G = gq[i & 3];
            if (i < 12)
                gq[i & 3] = *(const float4*)(gptr + (size_t)(i + 4) * 8 * J_DIM);

            float z0 = (L.x + G.x) * 2.0f;   // / TAU, TAU = 0.5
            float z1 = (L.y + G.y) * 2.0f;
            float z2 = (L.z + G.z) * 2.0f;
            float z3 = (L.w + G.w) * 2.0f;
            float gmax = fmaxf(fmaxf(z0, z1), fmaxf(z2, z3));
#pragma unroll
            for (int s = 1; s < 16; s <<= 1) gmax = fmaxf(gmax, __shfl_xor(gmax, s));

            const float e0 = __expf(z0 - gmax), e1 = __expf(z1 - gmax);
            const float e2 = __expf(z2 - gmax), e3 = __expf(z3 - gmax);
            float ss = e0 + e1 + e2 + e3;
            float ds = e0 * gridv.x + e1 * gridv.y + e2 * gridv.z + e3 * gridv.w;
#pragma unroll
            for (int s = 1; s < 16; s <<= 1) {
                ss += __shfl_xor(ss, s);
                ds += __shfl_xor(ds, s);
            }

            *(float4*)(lptr + (size_t)i * 8 * J_DIM) = L;
            if (lane15 == 0)
                encoded[(size_t)(row0 + h * 128 + r) * O_DIM + (col0 >> 6) + hi4] = ds / ss;
        }
        SBAR();   // reads of this half done before next half's writes
    }
}

// ---- fallback GEMM (ws too small): 128x128, on-the-fly bf16 pack -------
__global__ __launch_bounds__(256) void gemm_fb(
    const float* __restrict__ xf,
    const float* __restrict__ Wf,
    const float* __restrict__ bias,
    float* __restrict__ logits)
{
    __shared__ unsigned short Asm_[128 * 32];
    __shared__ unsigned short Bsm_[128 * 32];

    const int tid = threadIdx.x;
    const int bid = blockIdx.x;
    const int swz = (bid & 7) * 1024 + (bid >> 3);
    const int row0 = (swz >> 7) * 128;
    const int col0 = (swz & 127) * 128;

    const int lane = tid & 63;
    const int wid  = tid >> 6;
    const int wr   = wid >> 1;
    const int wc   = wid & 1;

    f32x4 acc[4][4];
#pragma unroll
    for (int m = 0; m < 4; ++m)
#pragma unroll
        for (int n = 0; n < 4; ++n)
            acc[m][n] = (f32x4){0.f, 0.f, 0.f, 0.f};

    const int srow = tid >> 2;
    const int koff = (tid & 3) * 8;
    const int ra0 = row0 + srow, ra1 = row0 + 64 + srow;
    const int rb0 = col0 + srow, rb1 = col0 + 64 + srow;

    unsigned short* la0 = &Asm_[tid * 8];
    unsigned short* la1 = &Asm_[(256 + tid) * 8];
    unsigned short* lb0 = &Bsm_[tid * 8];
    unsigned short* lb1 = &Bsm_[(256 + tid) * 8];

    const float* fa0 = xf + (size_t)ra0 * K_DIM + koff;
    const float* fa1 = xf + (size_t)ra1 * K_DIM + koff;
    const float* fb0 = Wf + (size_t)((rb0 & (O_DIM - 1)) * (N_BINS * K_DIM) + (rb0 >> 8) * K_DIM) + koff;
    const float* fb1 = Wf + (size_t)((rb1 & (O_DIM - 1)) * (N_BINS * K_DIM) + (rb1 >> 8) * K_DIM) + koff;

    const int a_row  = wr * 64 + (lane & 15);
    const int b_row  = wc * 64 + (lane & 15);
    const int k_half = (lane >> 4) * 8;

    for (int kt = 0; kt < K_DIM / 32; ++kt) {
        const int kbase = kt * 32;
        *(u16x8*)la0 = pack8(*(const float4*)(fa0 + kbase), *(const float4*)(fa0 + kbase + 4));
        *(u16x8*)la1 = pack8(*(const float4*)(fa1 + kbase), *(const float4*)(fa1 + kbase + 4));
        *(u16x8*)lb0 = pack8(*(const float4*)(fb0 + kbase), *(const float4*)(fb0 + kbase + 4));
        *(u16x8*)lb1 = pack8(*(const float4*)(fb1 + kbase), *(const float4*)(fb1 + kbase + 4));
        __syncthreads();
        bf16x8 af[4], bg[4];
#pragma unroll
        for (int m = 0; m < 4; ++m) af[m] = *(const bf16x8*)&Asm_[(a_row + m * 16) * 32 + k_half];
#pragma unroll
        for (int n = 0; n < 4; ++n) bg[n] = *(const bf16x8*)&Bsm_[(b_row + n * 16) * 32 + k_half];
#pragma unroll
        for (int m = 0; m < 4; ++m)
#pragma unroll
            for (int n = 0; n < 4; ++n)
                MFMA(af[m], bg[n], acc[m][n]);
        __syncthreads();
    }

    const int r_base = row0 + wr * 64 + (lane >> 4) * 4;
    const int c_base = col0 + wc * 64 + (lane & 15);
#pragma unroll
    for (int n = 0; n < 4; ++n) {
        const int c = c_base + n * 16;
        const float bv = bias[(c & (O_DIM - 1)) * N_BINS + (c >> 8)];
#pragma unroll
        for (int m = 0; m < 4; ++m) {
            const int r = r_base + m * 16;
            float* out = logits + (size_t)r * J_DIM + c;
#pragma unroll
            for (int q = 0; q < 4; ++q)
                out[(size_t)q * J_DIM] = acc[m][n][q] + bv;
        }
    }
}

// ---- standalone softmax (fallback path only) ---------------------------
__global__ void softmax_encode_kernel(
    const float* __restrict__ logits,
    const float* __restrict__ gumbel,
    const float* __restrict__ grid,
    float* __restrict__ encoded)
{
    int t = blockIdx.x * 256 + threadIdx.x;
    int g = t >> 4;
    int l = t & 15;
    size_t base = (size_t)g * 64 + l * 4;
    float4 L = *(const float4*)(logits + base);
    float4 G = *(const float4*)(gumbel + base);
    float4 gr = *(const float4*)(grid + l * 4);

    float z0 = (L.x + G.x) * 2.0f;
    float z1 = (L.y + G.y) * 2.0f;
    float z2 = (L.z + G.z) * 2.0f;
    float z3 = (L.w + G.w) * 2.0f;

    float m = fmaxf(fmaxf(z0, z1), fmaxf(z2, z3));
#pragma unroll
    for (int s = 1; s < 16; s <<= 1) m = fmaxf(m, __shfl_xor(m, s, 16));

    float e0 = __expf(z0 - m), e1 = __expf(z1 - m), e2 = __expf(z2 - m), e3 = __expf(z3 - m);
    float ssum = e0 + e1 + e2 + e3;
    float dsum = e0 * gr.x + e1 * gr.y + e2 * gr.z + e3 * gr.w;
#pragma unroll
    for (int s = 1; s < 16; s <<= 1) {
        ssum += __shfl_xor(ssum, s, 16);
        dsum += __shfl_xor(dsum, s, 16);
    }
    if (l == 0) encoded[g] = dsum / ssum;
}

// ---- launch -------------------------------------------------------------
extern "C" void kernel_launch(void* const* d_in, const int* in_sizes, int n_in,
                              void* d_out, int out_size, void* d_ws, size_t ws_size,
                              hipStream_t stream) {
    const float* x      = (const float*)d_in[0];
    const float* W      = (const float*)d_in[1];
    const float* bias   = (const float*)d_in[2];
    const float* grid   = (const float*)d_in[3];
    const float* gumbel = (const float*)d_in[4];

    float* encoded = (float*)d_out;                           // [8192][256]
    float* logits  = (float*)d_out + (size_t)B_ROWS * O_DIM;  // [8192][16384]

    const size_t xb_bytes = (size_t)B_ROWS * K_DIM * 2;   // 32 MiB
    const size_t vb_bytes = (size_t)J_DIM * K_DIM * 2;    // 64 MiB

    if (ws_size >= xb_bytes + vb_bytes) {
        unsigned short* xb = (unsigned short*)d_ws;
        unsigned short* vb = (unsigned short*)((char*)d_ws + xb_bytes);
        cvt_x_kernel<<<(B_ROWS * K_DIM) / 1024, 256, 0, stream>>>(x, xb);
        cvt_w_kernel<<<J_DIM * 2, 256, 0, stream>>>(W, vb);
        gemm8_kernel<<<(B_ROWS / 256) * (J_DIM / 256), 512, 0, stream>>>(
            xb, vb, bias, grid, gumbel, logits, encoded);
    } else {
        gemm_fb<<<(B_ROWS / 128) * (J_DIM / 128), 256, 0, stream>>>(x, W, bias, logits);
        softmax_encode_kernel<<<(B_ROWS * O_DIM * 16) / 256, 256, 0, stream>>>(logits, gumbel, grid, encoded);
    }
}